// Round 4
// baseline (61.002 us; speedup 1.0000x reference)
//
#include <hip/hip_runtime.h>

// Truncated path signature, trunc=4, D=8, B=128, S=512.
// Phase 0: dx precompute -> ws, padded to 512 rows/batch (row 511 = 0 = identity).
// Phase 1: 128 batches x 8 chunks x 64 steps, 512-thr blocks, barrier-free Chen
//          recurrence. dx ROW comes in via SGPRs (readfirstlane-uniform pointer ->
//          s_load; scalar operands feed the 8 level-4 FMAs). Per-lane picks db,dc
//          are LDS b32 broadcasts. da is wave-uniform (aa == wave id) -> scalar.
// Phase 2: 128 blocks fold the 8 chunk signatures (Chen product).
// Thread digits: aa=tid>>6 (== wave id), bb=(tid>>3)&7, cc=tid&7.

constexpr int Bc = 128, Sc = 512, Tc = 511;
constexpr int NCH = 8, CH = 64;
constexpr int SIGSZ = 8 + 64 + 512 + 4096;        // 4680 floats
constexpr int DXG_FLOATS = Bc * Sc * 8;           // 2 MiB, zero-padded tail row
constexpr int SIG_OFF = DXG_FLOATS;

__device__ __forceinline__ const float* uptr(const float* p) {
    uint64_t v = (uint64_t)p;
    uint32_t lo = __builtin_amdgcn_readfirstlane((uint32_t)v);
    uint32_t hi = __builtin_amdgcn_readfirstlane((uint32_t)(v >> 32));
    return (const float*)(((uint64_t)hi << 32) | lo);
}

// ---------------- Phase 0: dx precompute ----------------
__global__ __launch_bounds__(256)
void dx_pre(const float* __restrict__ path, float* __restrict__ dxg) {
    int i = blockIdx.x * 256 + threadIdx.x;
    if (i >= DXG_FLOATS) return;
    int b = i >> 12;
    int r = i & 4095;
    float v = 0.f;
    if (r < Tc * 8) {
        const float* p = path + ((size_t)b << 12);
        v = p[r + 8] - p[r];
    }
    dxg[i] = v;
}

// ---------------- Phase 1 inner loop ----------------
template <bool LOW>
__device__ __forceinline__ void chen_loop(
    const float* __restrict__ drow,   // uniform (SGPR) base of this chunk's dx rows
    const float* __restrict__ dxs,    // LDS copy for per-lane picks
    int wid, int bb, int cc,
    float acc4[8], float& acc3, float& s2ab,
    float& acc2, float& s1a, float& s1b, float& s1c)
{
#pragma unroll 4
    for (int t = 0; t < CH; ++t) {
        const float* r = drow + 8 * t;            // uniform -> s_load
        float d0 = r[0], d1 = r[1], d2 = r[2], d3 = r[3];
        float d4 = r[4], d5 = r[5], d6 = r[6], d7 = r[7];
        float da = r[wid];                        // uniform scalar load
        float db = dxs[8 * t + bb];               // LDS b32 broadcast
        float dc = dxs[8 * t + cc];               // LDS b32 broadcast

        float e = db * dc;
        float m = s2ab * dc;
        float v = fmaf(s1a, 1.f / 6.f, da * (1.f / 24.f));
        float K = fmaf(0.5f, m, acc3);
        K = fmaf(e, v, K);

        acc4[0] = fmaf(d0, K, acc4[0]);
        acc4[1] = fmaf(d1, K, acc4[1]);
        acc4[2] = fmaf(d2, K, acc4[2]);
        acc4[3] = fmaf(d3, K, acc4[3]);
        acc4[4] = fmaf(d4, K, acc4[4]);
        acc4[5] = fmaf(d5, K, acc4[5]);
        acc4[6] = fmaf(d6, K, acc4[6]);
        acc4[7] = fmaf(d7, K, acc4[7]);

        float w = fmaf(0.5f, s1a, da * (1.f / 6.f));
        acc3 = acc3 + m;
        acc3 = fmaf(e, w, acc3);

        if (LOW) {                                // compiled in only for wave 0
            acc2 = fmaf(s1b, dc, fmaf(0.5f, e, acc2));
            s1b += db; s1c += dc;
        }
        s2ab = fmaf(s1a, db, fmaf(0.5f * da, db, s2ab));
        s1a += da;
    }
}

// ---------------- Phase 1: per-chunk signature ----------------
__global__ __launch_bounds__(512)
void sig_chunk(const float* __restrict__ dxg, float* __restrict__ ws) {
    const int blk = blockIdx.x;
    const int b   = blk >> 3;
    const int c   = blk & 7;
    const int tid = threadIdx.x;

    const float* __restrict__ drow =
        uptr(dxg + (((size_t)b * Sc + c * CH) << 3));

    __shared__ float dxs[CH * 8];                 // 2 KiB
    dxs[tid] = drow[tid];                         // coalesced
    __syncthreads();

    const int bb  = (tid >> 3) & 7, cc = tid & 7;
    const int wid = __builtin_amdgcn_readfirstlane(tid) >> 6;

    float acc4[8] = {0.f, 0.f, 0.f, 0.f, 0.f, 0.f, 0.f, 0.f};
    float acc3 = 0.f, s2ab = 0.f, acc2 = 0.f;
    float s1a = 0.f, s1b = 0.f, s1c = 0.f;

    if (tid < 64) {                               // exactly wave 0
        chen_loop<true >(drow, dxs, wid, bb, cc, acc4, acc3, s2ab, acc2, s1a, s1b, s1c);
    } else {
        chen_loop<false>(drow, dxs, wid, bb, cc, acc4, acc3, s2ab, acc2, s1a, s1b, s1c);
    }

    float* o = ws + SIG_OFF + (size_t)blk * SIGSZ;
    if (tid < 8)  o[tid] = s1c;
    if (tid < 64) o[8 + tid] = acc2;
    o[72 + tid] = acc3;
    *(float4*)(o + 584 + 8 * tid)     = make_float4(acc4[0], acc4[1], acc4[2], acc4[3]);
    *(float4*)(o + 584 + 8 * tid + 4) = make_float4(acc4[4], acc4[5], acc4[6], acc4[7]);
}

// ---------------- Phase 2: fold chunk signatures ----------------
__global__ __launch_bounds__(512)
void sig_combine(const float* __restrict__ ws, float* __restrict__ out) {
    const int b = blockIdx.x, tid = threadIdx.x;
    const int aa = tid >> 6, bb = (tid >> 3) & 7, cc = tid & 7;

    float x4[8] = {0.f, 0.f, 0.f, 0.f, 0.f, 0.f, 0.f, 0.f};
    float x3 = 0.f, x2ab = 0.f, x2own = 0.f;
    float x1a = 0.f, x1b = 0.f, x1c = 0.f;

#pragma unroll 2
    for (int c = 0; c < NCH; ++c) {
        const float* y = ws + SIG_OFF + ((size_t)(b * NCH + c)) * SIGSZ;

        float y1a = y[aa], y1b = y[bb], y1c = y[cc];
        float y2ab = y[8 + 8 * aa + bb];
        float y2bc = y[8 + 8 * bb + cc];
        float4 y1lo = *(const float4*)y;
        float4 y1hi = *(const float4*)(y + 4);
        const float* y2r = y + 8 + 8 * cc;
        float4 y2lo = *(const float4*)y2r;
        float4 y2hi = *(const float4*)(y2r + 4);
        const float* y3r = y + 72 + 8 * (tid & 63);
        float4 y3lo = *(const float4*)y3r;
        float4 y3hi = *(const float4*)(y3r + 4);
        float y3own = y[72 + tid];
        const float* y4r = y + 584 + 8 * tid;
        float4 y4lo = *(const float4*)y4r;
        float4 y4hi = *(const float4*)(y4r + 4);

        x4[0] = x4[0] + x3 * y1lo.x + x2ab * y2lo.x + x1a * y3lo.x + y4lo.x;
        x4[1] = x4[1] + x3 * y1lo.y + x2ab * y2lo.y + x1a * y3lo.y + y4lo.y;
        x4[2] = x4[2] + x3 * y1lo.z + x2ab * y2lo.z + x1a * y3lo.z + y4lo.z;
        x4[3] = x4[3] + x3 * y1lo.w + x2ab * y2lo.w + x1a * y3lo.w + y4lo.w;
        x4[4] = x4[4] + x3 * y1hi.x + x2ab * y2hi.x + x1a * y3hi.x + y4hi.x;
        x4[5] = x4[5] + x3 * y1hi.y + x2ab * y2hi.y + x1a * y3hi.y + y4hi.y;
        x4[6] = x4[6] + x3 * y1hi.z + x2ab * y2hi.z + x1a * y3hi.z + y4hi.z;
        x4[7] = x4[7] + x3 * y1hi.w + x2ab * y2hi.w + x1a * y3hi.w + y4hi.w;

        x3 = x3 + x2ab * y1c + x1a * y2bc + y3own;
        x2ab  = x2ab  + x1a * y1b + y2ab;
        x2own = x2own + x1b * y1c + y2bc;
        x1a += y1a; x1b += y1b; x1c += y1c;
    }

    float* o = out + (size_t)b * SIGSZ;
    if (tid < 8)  o[tid] = x1c;
    if (tid < 64) o[8 + tid] = x2own;
    o[72 + tid] = x3;
    *(float4*)(o + 584 + 8 * tid)     = make_float4(x4[0], x4[1], x4[2], x4[3]);
    *(float4*)(o + 584 + 8 * tid + 4) = make_float4(x4[4], x4[5], x4[6], x4[7]);
}

// ---------------- Fallback (single-kernel, used if ws too small) ----------------
__global__ __launch_bounds__(512)
void sig_fallback(const float* __restrict__ path, float* __restrict__ out) {
    const int b = blockIdx.x, tid = threadIdx.x;
    __shared__ float dxAll[Tc * 8];
    const float* prow = path + (size_t)b * Sc * 8;
    for (int n = tid; n < Tc * 8; n += 512) dxAll[n] = prow[n + 8] - prow[n];
    __syncthreads();

    const int aa = tid >> 6, bb = (tid >> 3) & 7, cc = tid & 7;
    float acc4[8] = {0.f, 0.f, 0.f, 0.f, 0.f, 0.f, 0.f, 0.f};
    float acc3 = 0.f, s2ab = 0.f, acc2 = 0.f, s1a = 0.f, s1b = 0.f, s1c = 0.f;
    for (int t = 0; t < Tc; ++t) {
        const float* r = &dxAll[t * 8];
        float4 lo = *(const float4*)r;
        float4 hi = *(const float4*)(r + 4);
        float da = r[aa], db = r[bb], dc = r[cc];
        float e = db * dc;
        float K = acc3 + s2ab * (0.5f * dc) + e * fmaf(s1a, 1.f / 6.f, da * (1.f / 24.f));
        acc4[0] = fmaf(lo.x, K, acc4[0]);
        acc4[1] = fmaf(lo.y, K, acc4[1]);
        acc4[2] = fmaf(lo.z, K, acc4[2]);
        acc4[3] = fmaf(lo.w, K, acc4[3]);
        acc4[4] = fmaf(hi.x, K, acc4[4]);
        acc4[5] = fmaf(hi.y, K, acc4[5]);
        acc4[6] = fmaf(hi.z, K, acc4[6]);
        acc4[7] = fmaf(hi.w, K, acc4[7]);
        acc3 = acc3 + s2ab * dc + e * fmaf(0.5f, s1a, da * (1.f / 6.f));
        acc2 = fmaf(s1b, dc, fmaf(0.5f, e, acc2));
        s2ab = fmaf(s1a, db, fmaf(0.5f * da, db, s2ab));
        s1a += da; s1b += db; s1c += dc;
    }
    float* o = out + (size_t)b * SIGSZ;
    if (tid < 8)  o[tid] = s1c;
    if (tid < 64) o[8 + tid] = acc2;
    o[72 + tid] = acc3;
    *(float4*)(o + 584 + 8 * tid)     = make_float4(acc4[0], acc4[1], acc4[2], acc4[3]);
    *(float4*)(o + 584 + 8 * tid + 4) = make_float4(acc4[4], acc4[5], acc4[6], acc4[7]);
}

extern "C" void kernel_launch(void* const* d_in, const int* in_sizes, int n_in,
                              void* d_out, int out_size, void* d_ws, size_t ws_size,
                              hipStream_t stream) {
    const float* path = (const float*)d_in[0];
    float* out = (float*)d_out;
    const size_t need = (size_t)(DXG_FLOATS + Bc * NCH * SIGSZ) * sizeof(float);
    if (ws_size >= need) {
        float* ws = (float*)d_ws;
        dx_pre     <<<dim3((DXG_FLOATS + 255) / 256), dim3(256), 0, stream>>>(path, ws);
        sig_chunk  <<<dim3(Bc * NCH), dim3(512), 0, stream>>>(ws, ws);
        sig_combine<<<dim3(Bc), dim3(512), 0, stream>>>(ws, out);
    } else {
        sig_fallback<<<dim3(Bc), dim3(512), 0, stream>>>(path, out);
    }
}